// Round 5
// baseline (589.844 us; speedup 1.0000x reference)
//
#include <hip/hip_runtime.h>

// Problem constants: B=128, L=512, D=256, H=128, 4H=512, both dirs fused NG=1024
#define NB 128
#define NL 512
#define ND 256
#define NG 1024

typedef __attribute__((ext_vector_type(8))) short bfv8;
typedef __attribute__((ext_vector_type(4))) float f32x4;

__device__ __forceinline__ unsigned short f2bf(float f) {
    unsigned u = __float_as_uint(f);
    u += 0x7fffu + ((u >> 16) & 1u);   // round-to-nearest-even
    return (unsigned short)(u >> 16);
}
__device__ __forceinline__ float bf2f(unsigned short u) {
    return __uint_as_float(((unsigned)u) << 16);
}

// ---------------------------------------------------------------------------
// 1) convert+transpose: xbt[l*128+b][d] = bf16(x[b][l][d])
// ---------------------------------------------------------------------------
__global__ __launch_bounds__(256) void convert_kernel(const float* __restrict__ x,
                                                      unsigned short* __restrict__ xbt) {
    size_t t = (size_t)blockIdx.x * 256 + threadIdx.x;
    size_t e = t * 4;                       // flat idx into x, 4 floats per thread
    int d = (int)(e & 255u);
    int l = (int)((e >> 8) & 511u);
    int b = (int)(e >> 17);
    float4 v = *(const float4*)(x + e);
    ushort4 o;
    o.x = f2bf(v.x); o.y = f2bf(v.y); o.z = f2bf(v.z); o.w = f2bf(v.w);
    *(ushort4*)(xbt + ((size_t)(l * NB + b)) * ND + d) = o;
}

// ---------------------------------------------------------------------------
// 2) fold: Weff[g][k] = sum_d Wih[g][d] * W_proj[d][k]  (bf16 out)
//    beff[g] = b[g] + sum_d Wih[g][d] * b_proj[d]
// ---------------------------------------------------------------------------
__global__ __launch_bounds__(256) void fold_kernel(const float* __restrict__ Wproj,
                                                   const float* __restrict__ bproj,
                                                   const float* __restrict__ Wih_f,
                                                   const float* __restrict__ b_f,
                                                   const float* __restrict__ Wih_b,
                                                   const float* __restrict__ b_b,
                                                   unsigned short* __restrict__ weff,
                                                   float* __restrict__ beff) {
    int g = blockIdx.x;            // 0..1023
    int k = threadIdx.x;           // 0..255
    const float* Wih = (g < 512) ? (Wih_f + (size_t)g * ND) : (Wih_b + (size_t)(g - 512) * ND);
    float acc = 0.f;
    for (int d = 0; d < ND; ++d)
        acc += Wih[d] * Wproj[(size_t)d * ND + k];
    weff[(size_t)g * ND + k] = f2bf(acc);
    if (k == 0) {
        float ab = (g < 512) ? b_f[g] : b_b[g - 512];
        for (int d = 0; d < ND; ++d) ab += Wih[d] * bproj[d];
        beff[g] = ab;
    }
}

// ---------------------------------------------------------------------------
// 3) pre-GEMM: C[r][g] = bf16( A[r][:] . Bw[g][:] + bias[g] )
//    128x128 tile, BK=32, 4 waves (2x2), 16x16x32 bf16 MFMA, XOR-swizzled LDS
// ---------------------------------------------------------------------------
__global__ __launch_bounds__(256, 2) void gemm_pre(const unsigned short* __restrict__ A,
                                                   const unsigned short* __restrict__ Bw,
                                                   const float* __restrict__ bias,
                                                   unsigned short* __restrict__ C) {
    __shared__ unsigned short As[128 * 32];
    __shared__ unsigned short Bs[128 * 32];
    const int tid = threadIdx.x;
    const int lane = tid & 63;
    const int wid = tid >> 6;
    const int m0 = blockIdx.y * 128;
    const int n0 = blockIdx.x * 128;
    const int wm = (wid >> 1) * 64;
    const int wn = (wid & 1) * 64;

    f32x4 acc[4][4] = {};

    const int row0 = tid >> 2;               // 0..63
    const int row1 = row0 + 64;
    const int co = (tid & 3) * 8;            // element col offset (8 bf16 = 16B)
    const int sw = (((tid & 3) << 4) ^ ((row0 & 3) << 4)) >> 1;

    bfv8 ra0 = *(const bfv8*)(A + (size_t)(m0 + row0) * ND + co);
    bfv8 ra1 = *(const bfv8*)(A + (size_t)(m0 + row1) * ND + co);
    bfv8 rb0 = *(const bfv8*)(Bw + (size_t)(n0 + row0) * ND + co);
    bfv8 rb1 = *(const bfv8*)(Bw + (size_t)(n0 + row1) * ND + co);

    for (int it = 0; it < 8; ++it) {
        __syncthreads();
        *(bfv8*)(As + row0 * 32 + sw) = ra0;
        *(bfv8*)(As + row1 * 32 + sw) = ra1;
        *(bfv8*)(Bs + row0 * 32 + sw) = rb0;
        *(bfv8*)(Bs + row1 * 32 + sw) = rb1;
        const int k1 = ((it + 1) & 7) * 32;
        ra0 = *(const bfv8*)(A + (size_t)(m0 + row0) * ND + k1 + co);
        ra1 = *(const bfv8*)(A + (size_t)(m0 + row1) * ND + k1 + co);
        rb0 = *(const bfv8*)(Bw + (size_t)(n0 + row0) * ND + k1 + co);
        rb1 = *(const bfv8*)(Bw + (size_t)(n0 + row1) * ND + k1 + co);
        __syncthreads();

        const int r = lane & 15;
        const int kq = lane >> 4;
        bfv8 af[4], bfr[4];
        #pragma unroll
        for (int m = 0; m < 4; ++m) {
            int rw = wm + m * 16 + r;
            af[m] = *(const bfv8*)(As + rw * 32 + (((kq << 4) ^ ((rw & 3) << 4)) >> 1));
        }
        #pragma unroll
        for (int n = 0; n < 4; ++n) {
            int rw = wn + n * 16 + r;
            bfr[n] = *(const bfv8*)(Bs + rw * 32 + (((kq << 4) ^ ((rw & 3) << 4)) >> 1));
        }
        #pragma unroll
        for (int m = 0; m < 4; ++m)
            #pragma unroll
            for (int n = 0; n < 4; ++n)
                acc[m][n] = __builtin_amdgcn_mfma_f32_16x16x32_bf16(af[m], bfr[n], acc[m][n], 0, 0, 0);
    }

    const int r = lane & 15;
    const int rq = lane >> 4;
    #pragma unroll
    for (int n = 0; n < 4; ++n) {
        int col = n0 + wn + n * 16 + r;
        float bv = bias[col];
        #pragma unroll
        for (int m = 0; m < 4; ++m) {
            #pragma unroll
            for (int v = 0; v < 4; ++v) {
                int rowg = m0 + wm + m * 16 + rq * 4 + v;
                C[(size_t)rowg * NG + col] = f2bf(acc[m][n][v] + bv);
            }
        }
    }
}

// ---------------------------------------------------------------------------
// 4) LSTM scan: one block per (batch, dir). 512 threads: thread j = gate type
//    (j&3) of hidden unit (j>>2). 128 weights/thread in 32 named f32x4.
//    KEY FIX: amdgpu_waves_per_eu(2,2). The backend's scheduler targets the
//    MAX achievable occupancy and was spilling the weights to scratch to get
//    under the 64/128-VGPR breakpoints (VGPR_Count 48/80/84 across rounds ->
//    ~2400 cy/step of L2-bound scratch reloads). Grid is 1 block/CU anyway,
//    so capping occupancy at 2 waves/EU costs nothing and frees the full
//    256-VGPR budget. h broadcast from LDS (uniform addr, conflict-free),
//    double-buffered, gate exchange via shfl_xor -> ONE barrier per step.
// ---------------------------------------------------------------------------
__global__ void __launch_bounds__(512)
__attribute__((amdgpu_waves_per_eu(2, 2)))
scan_kernel(const unsigned short* __restrict__ pre,
            const float* __restrict__ Whh_f,
            const float* __restrict__ Whh_b,
            float* __restrict__ out) {
    const int b = blockIdx.x;
    const int dir = blockIdx.y;
    const int j = threadIdx.x;
    const int t4 = j & 3;            // gate type: 0=i,1=f,2=g,3=o
    const int hidx = j >> 2;         // hidden unit
    const int gidx = t4 * 128 + hidx;
    const float* __restrict__ Wr = (dir ? Whh_b : Whh_f) + (size_t)gidx * 128;

    __shared__ float hbuf[2][128];

#define WDECL(i) f32x4 w##i = *(const f32x4*)(Wr + 4 * (i));
    WDECL(0)  WDECL(1)  WDECL(2)  WDECL(3)  WDECL(4)  WDECL(5)  WDECL(6)  WDECL(7)
    WDECL(8)  WDECL(9)  WDECL(10) WDECL(11) WDECL(12) WDECL(13) WDECL(14) WDECL(15)
    WDECL(16) WDECL(17) WDECL(18) WDECL(19) WDECL(20) WDECL(21) WDECL(22) WDECL(23)
    WDECL(24) WDECL(25) WDECL(26) WDECL(27) WDECL(28) WDECL(29) WDECL(30) WDECL(31)
#undef WDECL

    if (j < 128) hbuf[0][j] = 0.f;
    float c = 0.f;
    const size_t pcol = (size_t)dir * 512 + gidx;
    const int tt0 = dir ? 511 : 0;
    float pnext = bf2f(pre[(size_t)(tt0 * NB + b) * NG + pcol]);
    __syncthreads();

    for (int s = 0; s < 512; ++s) {
        const int rb = s & 1;
        float gin = pnext;
        {   // prefetch next step's pre (independent of h -> hides HBM latency)
            int s1 = (s < 511) ? (s + 1) : 511;
            int tt1 = dir ? (511 - s1) : s1;
            pnext = bf2f(pre[(size_t)(tt1 * NB + b) * NG + pcol]);
        }
        const f32x4* hv = (const f32x4*)hbuf[rb];
        f32x4 a0 = w0 * hv[0];
        f32x4 a1 = w1 * hv[1];
        f32x4 a2 = w2 * hv[2];
        f32x4 a3 = w3 * hv[3];
#define DOT4(i0, i1, i2, i3) \
        a0 += w##i0 * hv[i0]; a1 += w##i1 * hv[i1]; \
        a2 += w##i2 * hv[i2]; a3 += w##i3 * hv[i3];
        DOT4(4, 5, 6, 7)     DOT4(8, 9, 10, 11)   DOT4(12, 13, 14, 15)
        DOT4(16, 17, 18, 19) DOT4(20, 21, 22, 23) DOT4(24, 25, 26, 27)
        DOT4(28, 29, 30, 31)
#undef DOT4
        f32x4 aa = (a0 + a1) + (a2 + a3);
        float g = gin + (aa.x + aa.y) + (aa.z + aa.w);

        // activation: sigmoid for i,f,o ; tanh for g
        float xg = (t4 == 2) ? 2.f * g : -g;
        float ev = __expf(xg);
        float act = (t4 == 2) ? (1.f - 2.f / (1.f + ev)) : (1.f / (1.f + ev));
        // exchange the 4 gate values within the 4-lane group
        float x0 = __shfl_xor(act, 1);   // type t^1
        float x1 = __shfl_xor(act, 2);   // type t^2
        float x2 = __shfl_xor(x0, 2);    // type t^3
        bool b0 = (t4 & 1) != 0, b1 = (t4 & 2) != 0;
        float gi = b1 ? (b0 ? x2 : x1) : (b0 ? x0 : act);
        float gf = b1 ? (b0 ? x1 : x2) : (b0 ? act : x0);
        float gg = b1 ? (b0 ? x0 : act) : (b0 ? x2 : x1);
        float go = b1 ? (b0 ? act : x0) : (b0 ? x1 : x2);
        c = gf * c + gi * gg;
        float th = 1.f - 2.f / (1.f + __expf(2.f * c));
        float h = go * th;
        if (t4 == 0) {
            int tt = dir ? (511 - s) : s;
            hbuf[1 - rb][hidx] = h;
            out[((size_t)b * NL + tt) * 256 + dir * 128 + hidx] = h;
        }
        __syncthreads();
    }
}

// ---------------------------------------------------------------------------
// 5) LayerNorm in-place over last dim (256); one wave per row
// ---------------------------------------------------------------------------
__global__ __launch_bounds__(256) void ln_kernel(float* __restrict__ out,
                                                 const float* __restrict__ gamma,
                                                 const float* __restrict__ beta) {
    int row = blockIdx.x * 4 + (threadIdx.x >> 6);
    int lane = threadIdx.x & 63;
    float* p = out + (size_t)row * 256;
    float4 v = ((const float4*)p)[lane];
    float s = (v.x + v.y) + (v.z + v.w);
    float s2 = (v.x * v.x + v.y * v.y) + (v.z * v.z + v.w * v.w);
    #pragma unroll
    for (int o = 32; o > 0; o >>= 1) {
        s += __shfl_xor(s, o);
        s2 += __shfl_xor(s2, o);
    }
    float mu = s * (1.f / 256.f);
    float var = s2 * (1.f / 256.f) - mu * mu;
    float rs = rsqrtf(var + 1e-5f);
    float4 gv = ((const float4*)gamma)[lane];
    float4 bv = ((const float4*)beta)[lane];
    float4 r;
    r.x = (v.x - mu) * rs * gv.x + bv.x;
    r.y = (v.y - mu) * rs * gv.y + bv.y;
    r.z = (v.z - mu) * rs * gv.z + bv.z;
    r.w = (v.w - mu) * rs * gv.w + bv.w;
    ((float4*)p)[lane] = r;
}

// ---------------------------------------------------------------------------
extern "C" void kernel_launch(void* const* d_in, const int* in_sizes, int n_in,
                              void* d_out, int out_size, void* d_ws, size_t ws_size,
                              hipStream_t stream) {
    (void)in_sizes; (void)n_in; (void)out_size; (void)ws_size;
    const float* x     = (const float*)d_in[0];
    const float* Wproj = (const float*)d_in[1];
    const float* bproj = (const float*)d_in[2];
    const float* Wih_f = (const float*)d_in[3];
    const float* Whh_f = (const float*)d_in[4];
    const float* b_f   = (const float*)d_in[5];
    const float* Wih_b = (const float*)d_in[6];
    const float* Whh_b = (const float*)d_in[7];
    const float* b_b   = (const float*)d_in[8];
    const float* gamma = (const float*)d_in[9];
    const float* beta  = (const float*)d_in[10];
    float* out = (float*)d_out;

    // workspace layout
    char* ws = (char*)d_ws;
    unsigned short* pre  = (unsigned short*)ws;                   // 65536*1024*2 = 134217728
    unsigned short* xbt  = (unsigned short*)(ws + 134217728);     // 65536*256*2  =  33554432
    unsigned short* weff = (unsigned short*)(ws + 167772160);     // 1024*256*2   =    524288
    float*          beff = (float*)(ws + 168296448);              // 1024*4

    convert_kernel<<<16384, 256, 0, stream>>>(x, xbt);
    fold_kernel<<<1024, 256, 0, stream>>>(Wproj, bproj, Wih_f, b_f, Wih_b, b_b, weff, beff);
    gemm_pre<<<dim3(8, 512), 256, 0, stream>>>(xbt, weff, beff, pre);
    scan_kernel<<<dim3(128, 2), 512, 0, stream>>>(pre, Whh_f, Whh_b, out);
    ln_kernel<<<16384, 256, 0, stream>>>(out, gamma, beta);
}

// Round 6
// 586.571 us; speedup vs baseline: 1.0056x; 1.0056x over previous
//
#include <hip/hip_runtime.h>

// Problem constants: B=128, L=512, D=256, H=128, 4H=512, both dirs fused NG=1024
#define NB 128
#define NL 512
#define ND 256
#define NG 1024

typedef __attribute__((ext_vector_type(8))) short bfv8;
typedef __attribute__((ext_vector_type(4))) float f32x4;
typedef __attribute__((ext_vector_type(4))) unsigned u32x4;

__device__ __forceinline__ unsigned short f2bf(float f) {
    unsigned u = __float_as_uint(f);
    u += 0x7fffu + ((u >> 16) & 1u);   // round-to-nearest-even
    return (unsigned short)(u >> 16);
}
__device__ __forceinline__ float bf2f(unsigned short u) {
    return __uint_as_float(((unsigned)u) << 16);
}

// ---------------------------------------------------------------------------
// 1) convert+transpose: xbt[l*128+b][d] = bf16(x[b][l][d])
// ---------------------------------------------------------------------------
__global__ __launch_bounds__(256) void convert_kernel(const float* __restrict__ x,
                                                      unsigned short* __restrict__ xbt) {
    size_t t = (size_t)blockIdx.x * 256 + threadIdx.x;
    size_t e = t * 4;                       // flat idx into x, 4 floats per thread
    int d = (int)(e & 255u);
    int l = (int)((e >> 8) & 511u);
    int b = (int)(e >> 17);
    float4 v = *(const float4*)(x + e);
    ushort4 o;
    o.x = f2bf(v.x); o.y = f2bf(v.y); o.z = f2bf(v.z); o.w = f2bf(v.w);
    *(ushort4*)(xbt + ((size_t)(l * NB + b)) * ND + d) = o;
}

// ---------------------------------------------------------------------------
// 2) fold: Weff[g][k] = sum_d Wih[g][d] * W_proj[d][k]  (bf16 out)
//    beff[g] = b[g] + sum_d Wih[g][d] * b_proj[d]
// ---------------------------------------------------------------------------
__global__ __launch_bounds__(256) void fold_kernel(const float* __restrict__ Wproj,
                                                   const float* __restrict__ bproj,
                                                   const float* __restrict__ Wih_f,
                                                   const float* __restrict__ b_f,
                                                   const float* __restrict__ Wih_b,
                                                   const float* __restrict__ b_b,
                                                   unsigned short* __restrict__ weff,
                                                   float* __restrict__ beff) {
    int g = blockIdx.x;            // 0..1023
    int k = threadIdx.x;           // 0..255
    const float* Wih = (g < 512) ? (Wih_f + (size_t)g * ND) : (Wih_b + (size_t)(g - 512) * ND);
    float acc = 0.f;
    for (int d = 0; d < ND; ++d)
        acc += Wih[d] * Wproj[(size_t)d * ND + k];
    weff[(size_t)g * ND + k] = f2bf(acc);
    if (k == 0) {
        float ab = (g < 512) ? b_f[g] : b_b[g - 512];
        for (int d = 0; d < ND; ++d) ab += Wih[d] * bproj[d];
        beff[g] = ab;
    }
}

// ---------------------------------------------------------------------------
// 3) pre-GEMM: C[r][g] = bf16( A[r][:] . Bw[g][:] + bias[g] )
//    128x128 tile, BK=32, 4 waves (2x2), 16x16x32 bf16 MFMA, XOR-swizzled LDS
// ---------------------------------------------------------------------------
__global__ __launch_bounds__(256, 2) void gemm_pre(const unsigned short* __restrict__ A,
                                                   const unsigned short* __restrict__ Bw,
                                                   const float* __restrict__ bias,
                                                   unsigned short* __restrict__ C) {
    __shared__ unsigned short As[128 * 32];
    __shared__ unsigned short Bs[128 * 32];
    const int tid = threadIdx.x;
    const int lane = tid & 63;
    const int wid = tid >> 6;
    const int m0 = blockIdx.y * 128;
    const int n0 = blockIdx.x * 128;
    const int wm = (wid >> 1) * 64;
    const int wn = (wid & 1) * 64;

    f32x4 acc[4][4] = {};

    const int row0 = tid >> 2;               // 0..63
    const int row1 = row0 + 64;
    const int co = (tid & 3) * 8;            // element col offset (8 bf16 = 16B)
    const int sw = (((tid & 3) << 4) ^ ((row0 & 3) << 4)) >> 1;

    bfv8 ra0 = *(const bfv8*)(A + (size_t)(m0 + row0) * ND + co);
    bfv8 ra1 = *(const bfv8*)(A + (size_t)(m0 + row1) * ND + co);
    bfv8 rb0 = *(const bfv8*)(Bw + (size_t)(n0 + row0) * ND + co);
    bfv8 rb1 = *(const bfv8*)(Bw + (size_t)(n0 + row1) * ND + co);

    for (int it = 0; it < 8; ++it) {
        __syncthreads();
        *(bfv8*)(As + row0 * 32 + sw) = ra0;
        *(bfv8*)(As + row1 * 32 + sw) = ra1;
        *(bfv8*)(Bs + row0 * 32 + sw) = rb0;
        *(bfv8*)(Bs + row1 * 32 + sw) = rb1;
        const int k1 = ((it + 1) & 7) * 32;
        ra0 = *(const bfv8*)(A + (size_t)(m0 + row0) * ND + k1 + co);
        ra1 = *(const bfv8*)(A + (size_t)(m0 + row1) * ND + k1 + co);
        rb0 = *(const bfv8*)(Bw + (size_t)(n0 + row0) * ND + k1 + co);
        rb1 = *(const bfv8*)(Bw + (size_t)(n0 + row1) * ND + k1 + co);
        __syncthreads();

        const int r = lane & 15;
        const int kq = lane >> 4;
        bfv8 af[4], bfr[4];
        #pragma unroll
        for (int m = 0; m < 4; ++m) {
            int rw = wm + m * 16 + r;
            af[m] = *(const bfv8*)(As + rw * 32 + (((kq << 4) ^ ((rw & 3) << 4)) >> 1));
        }
        #pragma unroll
        for (int n = 0; n < 4; ++n) {
            int rw = wn + n * 16 + r;
            bfr[n] = *(const bfv8*)(Bs + rw * 32 + (((kq << 4) ^ ((rw & 3) << 4)) >> 1));
        }
        #pragma unroll
        for (int m = 0; m < 4; ++m)
            #pragma unroll
            for (int n = 0; n < 4; ++n)
                acc[m][n] = __builtin_amdgcn_mfma_f32_16x16x32_bf16(af[m], bfr[n], acc[m][n], 0, 0, 0);
    }

    const int r = lane & 15;
    const int rq = lane >> 4;
    #pragma unroll
    for (int n = 0; n < 4; ++n) {
        int col = n0 + wn + n * 16 + r;
        float bv = bias[col];
        #pragma unroll
        for (int m = 0; m < 4; ++m) {
            #pragma unroll
            for (int v = 0; v < 4; ++v) {
                int rowg = m0 + wm + m * 16 + rq * 4 + v;
                C[(size_t)rowg * NG + col] = f2bf(acc[m][n][v] + bv);
            }
        }
    }
}

// ---------------------------------------------------------------------------
// 4) LSTM scan, LDS-return-bandwidth optimized.
//    Diagnosis: broadcast ds_read returns 64 lanes x 16B regardless of address
//    sharing -> old structure moved 256KB/CU/step through the ~128B/cy LDS
//    return path (2048cy, matches all measured rounds). New layout splits K:
//    thread j: hh=j>>2 owns all 4 gate rows (i,f,g,o) of hidden unit hh,
//    kc=j&3 owns a 32-element h chunk. Each lane reads only 64B of bf16 h
//    (4x b128 -> 32KB/CU/step), dots with bf16-packed weights (64 VGPRs ->
//    fits under the allocator's 128-VGPR target, no spill pressure), then a
//    2-stage shfl_xor allreduce over kc gives all 4 gate sums to all 4 lanes;
//    c,h computed redundantly per 4-lane group. ONE barrier per step.
// ---------------------------------------------------------------------------
#define DOT2(p, w, h) asm("v_dot2_f32_bf16 %0, %1, %2, %0" : "+v"(p) : "v"(w), "v"(h))

__global__ void __launch_bounds__(512)
scan_kernel(const unsigned short* __restrict__ pre,
            const float* __restrict__ Whh_f,
            const float* __restrict__ Whh_b,
            float* __restrict__ out) {
    const int b = blockIdx.x;
    const int dir = blockIdx.y;
    const int j = threadIdx.x;
    const int kc = j & 3;            // K-chunk: h[32*kc .. 32*kc+32)
    const int hh = j >> 2;           // hidden unit

    const float* __restrict__ Wd = dir ? Whh_b : Whh_f;

    __shared__ unsigned short hbuf[2][128];   // bf16 h, double buffered

    // pack weights bf16: wp[t][d] = (w[2d+1]<<16)|w[2d], rows t*128+hh, cols kc*32..
    unsigned wp[4][16];
    #pragma unroll
    for (int t = 0; t < 4; ++t) {
        const float4* wr = (const float4*)(Wd + (size_t)(t * 128 + hh) * 128 + kc * 32);
        #pragma unroll
        for (int q = 0; q < 8; ++q) {
            float4 v = wr[q];
            wp[t][2 * q]     = (unsigned)f2bf(v.x) | ((unsigned)f2bf(v.y) << 16);
            wp[t][2 * q + 1] = (unsigned)f2bf(v.z) | ((unsigned)f2bf(v.w) << 16);
        }
    }

    if (j < 128) { hbuf[0][j] = 0; hbuf[1][j] = 0; }
    float c = 0.f;
    const int tt0 = dir ? 511 : 0;
    const size_t pbase = (size_t)dir * 512 + hh;
    const unsigned short* pp = pre + (size_t)(tt0 * NB + b) * NG + pbase;
    float pn0 = bf2f(pp[0]), pn1 = bf2f(pp[128]), pn2 = bf2f(pp[256]), pn3 = bf2f(pp[384]);
    __syncthreads();

    for (int s = 0; s < 512; ++s) {
        const int rb = s & 1;
        float g0 = pn0, g1 = pn1, g2 = pn2, g3 = pn3;
        {   // prefetch next step's pre (independent of h)
            int s1 = (s < 511) ? (s + 1) : 511;
            int tt1 = dir ? (511 - s1) : s1;
            const unsigned short* q = pre + (size_t)(tt1 * NB + b) * NG + pbase;
            pn0 = bf2f(q[0]); pn1 = bf2f(q[128]); pn2 = bf2f(q[256]); pn3 = bf2f(q[384]);
        }
        // my 64B chunk of h: 4 x ds_read_b128
        const bfv8* hv8 = (const bfv8*)&hbuf[rb][kc * 32];
        u32x4 hu0 = __builtin_bit_cast(u32x4, hv8[0]);
        u32x4 hu1 = __builtin_bit_cast(u32x4, hv8[1]);
        u32x4 hu2 = __builtin_bit_cast(u32x4, hv8[2]);
        u32x4 hu3 = __builtin_bit_cast(u32x4, hv8[3]);

        float p0 = 0.f, p1 = 0.f, p2 = 0.f, p3 = 0.f;
#define DOTBLK(d, hw) \
        DOT2(p0, wp[0][d], hw); DOT2(p1, wp[1][d], hw); \
        DOT2(p2, wp[2][d], hw); DOT2(p3, wp[3][d], hw);
        DOTBLK(0,  hu0.x) DOTBLK(1,  hu0.y) DOTBLK(2,  hu0.z) DOTBLK(3,  hu0.w)
        DOTBLK(4,  hu1.x) DOTBLK(5,  hu1.y) DOTBLK(6,  hu1.z) DOTBLK(7,  hu1.w)
        DOTBLK(8,  hu2.x) DOTBLK(9,  hu2.y) DOTBLK(10, hu2.z) DOTBLK(11, hu2.w)
        DOTBLK(12, hu3.x) DOTBLK(13, hu3.y) DOTBLK(14, hu3.z) DOTBLK(15, hu3.w)
#undef DOTBLK

        // allreduce partial dots over the 4 kc lanes (j bits 0-1)
        p0 += __shfl_xor(p0, 1); p0 += __shfl_xor(p0, 2);
        p1 += __shfl_xor(p1, 1); p1 += __shfl_xor(p1, 2);
        p2 += __shfl_xor(p2, 1); p2 += __shfl_xor(p2, 2);
        p3 += __shfl_xor(p3, 1); p3 += __shfl_xor(p3, 2);

        float si = g0 + p0;   // input gate (pre-activation)
        float sf = g1 + p1;   // forget
        float sg = g2 + p2;   // cell
        float so = g3 + p3;   // output
        float ia = 1.f / (1.f + __expf(-si));
        float fa = 1.f / (1.f + __expf(-sf));
        float ga = 1.f - 2.f / (1.f + __expf(2.f * sg));   // tanh
        float oa = 1.f / (1.f + __expf(-so));
        c = fa * c + ia * ga;
        float th = 1.f - 2.f / (1.f + __expf(2.f * c));
        float h = oa * th;
        if (kc == 0) {
            int tt = dir ? (511 - s) : s;
            out[((size_t)b * NL + tt) * 256 + dir * 128 + hh] = h;
            hbuf[1 - rb][hh] = f2bf(h);
        }
        __syncthreads();
    }
}

// ---------------------------------------------------------------------------
// 5) LayerNorm in-place over last dim (256); one wave per row
// ---------------------------------------------------------------------------
__global__ __launch_bounds__(256) void ln_kernel(float* __restrict__ out,
                                                 const float* __restrict__ gamma,
                                                 const float* __restrict__ beta) {
    int row = blockIdx.x * 4 + (threadIdx.x >> 6);
    int lane = threadIdx.x & 63;
    float* p = out + (size_t)row * 256;
    float4 v = ((const float4*)p)[lane];
    float s = (v.x + v.y) + (v.z + v.w);
    float s2 = (v.x * v.x + v.y * v.y) + (v.z * v.z + v.w * v.w);
    #pragma unroll
    for (int o = 32; o > 0; o >>= 1) {
        s += __shfl_xor(s, o);
        s2 += __shfl_xor(s2, o);
    }
    float mu = s * (1.f / 256.f);
    float var = s2 * (1.f / 256.f) - mu * mu;
    float rs = rsqrtf(var + 1e-5f);
    float4 gv = ((const float4*)gamma)[lane];
    float4 bv = ((const float4*)beta)[lane];
    float4 r;
    r.x = (v.x - mu) * rs * gv.x + bv.x;
    r.y = (v.y - mu) * rs * gv.y + bv.y;
    r.z = (v.z - mu) * rs * gv.z + bv.z;
    r.w = (v.w - mu) * rs * gv.w + bv.w;
    ((float4*)p)[lane] = r;
}

// ---------------------------------------------------------------------------
extern "C" void kernel_launch(void* const* d_in, const int* in_sizes, int n_in,
                              void* d_out, int out_size, void* d_ws, size_t ws_size,
                              hipStream_t stream) {
    (void)in_sizes; (void)n_in; (void)out_size; (void)ws_size;
    const float* x     = (const float*)d_in[0];
    const float* Wproj = (const float*)d_in[1];
    const float* bproj = (const float*)d_in[2];
    const float* Wih_f = (const float*)d_in[3];
    const float* Whh_f = (const float*)d_in[4];
    const float* b_f   = (const float*)d_in[5];
    const float* Wih_b = (const float*)d_in[6];
    const float* Whh_b = (const float*)d_in[7];
    const float* b_b   = (const float*)d_in[8];
    const float* gamma = (const float*)d_in[9];
    const float* beta  = (const float*)d_in[10];
    float* out = (float*)d_out;

    // workspace layout
    char* ws = (char*)d_ws;
    unsigned short* pre  = (unsigned short*)ws;                   // 65536*1024*2 = 134217728
    unsigned short* xbt  = (unsigned short*)(ws + 134217728);     // 65536*256*2  =  33554432
    unsigned short* weff = (unsigned short*)(ws + 167772160);     // 1024*256*2   =    524288
    float*          beff = (float*)(ws + 168296448);              // 1024*4

    convert_kernel<<<16384, 256, 0, stream>>>(x, xbt);
    fold_kernel<<<1024, 256, 0, stream>>>(Wproj, bproj, Wih_f, b_f, Wih_b, b_b, weff, beff);
    gemm_pre<<<dim3(8, 512), 256, 0, stream>>>(xbt, weff, beff, pre);
    scan_kernel<<<dim3(128, 2), 512, 0, stream>>>(pre, Whh_f, Whh_b, out);
    ln_kernel<<<16384, 256, 0, stream>>>(out, gamma, beta);
}

// Round 7
// 582.554 us; speedup vs baseline: 1.0125x; 1.0069x over previous
//
#include <hip/hip_runtime.h>

// Problem constants: B=128, L=512, D=256, H=128, 4H=512, both dirs fused NG=1024
#define NB 128
#define NL 512
#define ND 256
#define NG 1024

typedef __attribute__((ext_vector_type(8))) short bfv8;
typedef __attribute__((ext_vector_type(4))) float f32x4;
typedef __attribute__((ext_vector_type(4))) unsigned u32x4;

__device__ __forceinline__ unsigned short f2bf(float f) {
    unsigned u = __float_as_uint(f);
    u += 0x7fffu + ((u >> 16) & 1u);   // round-to-nearest-even
    return (unsigned short)(u >> 16);
}
__device__ __forceinline__ float bf2f(unsigned short u) {
    return __uint_as_float(((unsigned)u) << 16);
}

// ---------------------------------------------------------------------------
// 1) convert+transpose: xbt[l*128+b][d] = bf16(x[b][l][d])
// ---------------------------------------------------------------------------
__global__ __launch_bounds__(256) void convert_kernel(const float* __restrict__ x,
                                                      unsigned short* __restrict__ xbt) {
    size_t t = (size_t)blockIdx.x * 256 + threadIdx.x;
    size_t e = t * 4;                       // flat idx into x, 4 floats per thread
    int d = (int)(e & 255u);
    int l = (int)((e >> 8) & 511u);
    int b = (int)(e >> 17);
    float4 v = *(const float4*)(x + e);
    ushort4 o;
    o.x = f2bf(v.x); o.y = f2bf(v.y); o.z = f2bf(v.z); o.w = f2bf(v.w);
    *(ushort4*)(xbt + ((size_t)(l * NB + b)) * ND + d) = o;
}

// ---------------------------------------------------------------------------
// 2) fold: Weff[g][k] = sum_d Wih[g][d] * W_proj[d][k]  (bf16 out)
//    beff[g] = b[g] + sum_d Wih[g][d] * b_proj[d]
// ---------------------------------------------------------------------------
__global__ __launch_bounds__(256) void fold_kernel(const float* __restrict__ Wproj,
                                                   const float* __restrict__ bproj,
                                                   const float* __restrict__ Wih_f,
                                                   const float* __restrict__ b_f,
                                                   const float* __restrict__ Wih_b,
                                                   const float* __restrict__ b_b,
                                                   unsigned short* __restrict__ weff,
                                                   float* __restrict__ beff) {
    int g = blockIdx.x;            // 0..1023
    int k = threadIdx.x;           // 0..255
    const float* Wih = (g < 512) ? (Wih_f + (size_t)g * ND) : (Wih_b + (size_t)(g - 512) * ND);
    float acc = 0.f;
    for (int d = 0; d < ND; ++d)
        acc += Wih[d] * Wproj[(size_t)d * ND + k];
    weff[(size_t)g * ND + k] = f2bf(acc);
    if (k == 0) {
        float ab = (g < 512) ? b_f[g] : b_b[g - 512];
        for (int d = 0; d < ND; ++d) ab += Wih[d] * bproj[d];
        beff[g] = ab;
    }
}

// ---------------------------------------------------------------------------
// 3) pre-GEMM: C[r][g] = bf16( A[r][:] . Bw[g][:] + bias[g] )
//    128x128 tile, BK=32, 4 waves (2x2), 16x16x32 bf16 MFMA, XOR-swizzled LDS
// ---------------------------------------------------------------------------
__global__ __launch_bounds__(256, 2) void gemm_pre(const unsigned short* __restrict__ A,
                                                   const unsigned short* __restrict__ Bw,
                                                   const float* __restrict__ bias,
                                                   unsigned short* __restrict__ C) {
    __shared__ unsigned short As[128 * 32];
    __shared__ unsigned short Bs[128 * 32];
    const int tid = threadIdx.x;
    const int lane = tid & 63;
    const int wid = tid >> 6;
    const int m0 = blockIdx.y * 128;
    const int n0 = blockIdx.x * 128;
    const int wm = (wid >> 1) * 64;
    const int wn = (wid & 1) * 64;

    f32x4 acc[4][4] = {};

    const int row0 = tid >> 2;               // 0..63
    const int row1 = row0 + 64;
    const int co = (tid & 3) * 8;            // element col offset (8 bf16 = 16B)
    const int sw = (((tid & 3) << 4) ^ ((row0 & 3) << 4)) >> 1;

    bfv8 ra0 = *(const bfv8*)(A + (size_t)(m0 + row0) * ND + co);
    bfv8 ra1 = *(const bfv8*)(A + (size_t)(m0 + row1) * ND + co);
    bfv8 rb0 = *(const bfv8*)(Bw + (size_t)(n0 + row0) * ND + co);
    bfv8 rb1 = *(const bfv8*)(Bw + (size_t)(n0 + row1) * ND + co);

    for (int it = 0; it < 8; ++it) {
        __syncthreads();
        *(bfv8*)(As + row0 * 32 + sw) = ra0;
        *(bfv8*)(As + row1 * 32 + sw) = ra1;
        *(bfv8*)(Bs + row0 * 32 + sw) = rb0;
        *(bfv8*)(Bs + row1 * 32 + sw) = rb1;
        const int k1 = ((it + 1) & 7) * 32;
        ra0 = *(const bfv8*)(A + (size_t)(m0 + row0) * ND + k1 + co);
        ra1 = *(const bfv8*)(A + (size_t)(m0 + row1) * ND + k1 + co);
        rb0 = *(const bfv8*)(Bw + (size_t)(n0 + row0) * ND + k1 + co);
        rb1 = *(const bfv8*)(Bw + (size_t)(n0 + row1) * ND + k1 + co);
        __syncthreads();

        const int r = lane & 15;
        const int kq = lane >> 4;
        bfv8 af[4], bfr[4];
        #pragma unroll
        for (int m = 0; m < 4; ++m) {
            int rw = wm + m * 16 + r;
            af[m] = *(const bfv8*)(As + rw * 32 + (((kq << 4) ^ ((rw & 3) << 4)) >> 1));
        }
        #pragma unroll
        for (int n = 0; n < 4; ++n) {
            int rw = wn + n * 16 + r;
            bfr[n] = *(const bfv8*)(Bs + rw * 32 + (((kq << 4) ^ ((rw & 3) << 4)) >> 1));
        }
        #pragma unroll
        for (int m = 0; m < 4; ++m)
            #pragma unroll
            for (int n = 0; n < 4; ++n)
                acc[m][n] = __builtin_amdgcn_mfma_f32_16x16x32_bf16(af[m], bfr[n], acc[m][n], 0, 0, 0);
    }

    const int r = lane & 15;
    const int rq = lane >> 4;
    #pragma unroll
    for (int n = 0; n < 4; ++n) {
        int col = n0 + wn + n * 16 + r;
        float bv = bias[col];
        #pragma unroll
        for (int m = 0; m < 4; ++m) {
            #pragma unroll
            for (int v = 0; v < 4; ++v) {
                int rowg = m0 + wm + m * 16 + rq * 4 + v;
                C[(size_t)rowg * NG + col] = f2bf(acc[m][n][v] + bv);
            }
        }
    }
}

// ---------------------------------------------------------------------------
// 4) LSTM scan (round-6 K-split structure) + OCCUPANCY PIN via LDS.
//    Diagnosis across r1-r6: the register allocator statically targets MAX
//    theoretical occupancy (VGPR_Count always lands just under a waves/EU
//    breakpoint: 48->8/EU, 72-88->6/EU) and spills/remats the 64 packed
//    weight dwords -> ~64 reloads/step (VALUBusy 67% of 2370cy/step is
//    reload+addressing code). launch_bounds/waves_per_eu only cap regs, they
//    don't stop spilling-for-occupancy. Fix: allocate >80KiB LDS so TWO
//    512-thread blocks can never co-reside -> static max occupancy becomes
//    8 waves/CU (2/EU) -> allocator budget 256 VGPR -> weights stay resident.
//    Runtime cost: none (grid = 256 blocks = 1/CU already).
//    Layout: thread j: hh=j>>2 owns all 4 gate rows of hidden unit hh,
//    kc=j&3 owns a 32-elem h chunk (64B bf16 ds_read); 16 v_dot2_f32_bf16
//    per gate row; 2-stage shfl_xor allreduce over kc; ONE barrier/step.
// ---------------------------------------------------------------------------
#define DOT2(p, w, h) asm("v_dot2_f32_bf16 %0, %1, %2, %0" : "+v"(p) : "v"(w), "v"(h))

__global__ void __launch_bounds__(512, 2)
scan_kernel(const unsigned short* __restrict__ pre,
            const float* __restrict__ Whh_f,
            const float* __restrict__ Whh_b,
            float* __restrict__ out) {
    const int b = blockIdx.x;
    const int dir = blockIdx.y;
    const int j = threadIdx.x;
    const int kc = j & 3;            // K-chunk: h[32*kc .. 32*kc+32)
    const int hh = j >> 2;           // hidden unit

    const float* __restrict__ Wd = dir ? Whh_b : Whh_f;

    // hbuf plus padding to push block LDS above 80 KiB (163840/2 = 81920):
    // 512B hbuf + 82176B pad = 82688B -> statically only 1 block/CU fits.
    __shared__ struct {
        unsigned short hbuf[2][128];   // bf16 h, double buffered
        char occupancy_pin[82176];
    } sm;

    // pack weights bf16: wp[t][d] = (w[2d+1]<<16)|w[2d], rows t*128+hh, cols kc*32..
    unsigned wp[4][16];
    #pragma unroll
    for (int t = 0; t < 4; ++t) {
        const float4* wr = (const float4*)(Wd + (size_t)(t * 128 + hh) * 128 + kc * 32);
        #pragma unroll
        for (int q = 0; q < 8; ++q) {
            float4 v = wr[q];
            wp[t][2 * q]     = (unsigned)f2bf(v.x) | ((unsigned)f2bf(v.y) << 16);
            wp[t][2 * q + 1] = (unsigned)f2bf(v.z) | ((unsigned)f2bf(v.w) << 16);
        }
    }

    if (j < 128) { sm.hbuf[0][j] = 0; sm.hbuf[1][j] = 0; }
    float c = 0.f;
    const int tt0 = dir ? 511 : 0;
    const size_t pbase = (size_t)dir * 512 + hh;
    const unsigned short* pp = pre + (size_t)(tt0 * NB + b) * NG + pbase;
    float pn0 = bf2f(pp[0]), pn1 = bf2f(pp[128]), pn2 = bf2f(pp[256]), pn3 = bf2f(pp[384]);
    __syncthreads();

    for (int s = 0; s < 512; ++s) {
        const int rb = s & 1;
        float g0 = pn0, g1 = pn1, g2 = pn2, g3 = pn3;
        {   // prefetch next step's pre (independent of h)
            int s1 = (s < 511) ? (s + 1) : 511;
            int tt1 = dir ? (511 - s1) : s1;
            const unsigned short* q = pre + (size_t)(tt1 * NB + b) * NG + pbase;
            pn0 = bf2f(q[0]); pn1 = bf2f(q[128]); pn2 = bf2f(q[256]); pn3 = bf2f(q[384]);
        }
        // my 64B chunk of h: 4 x ds_read_b128
        const bfv8* hv8 = (const bfv8*)&sm.hbuf[rb][kc * 32];
        u32x4 hu0 = __builtin_bit_cast(u32x4, hv8[0]);
        u32x4 hu1 = __builtin_bit_cast(u32x4, hv8[1]);
        u32x4 hu2 = __builtin_bit_cast(u32x4, hv8[2]);
        u32x4 hu3 = __builtin_bit_cast(u32x4, hv8[3]);

        float p0 = 0.f, p1 = 0.f, p2 = 0.f, p3 = 0.f;
#define DOTBLK(d, hw) \
        DOT2(p0, wp[0][d], hw); DOT2(p1, wp[1][d], hw); \
        DOT2(p2, wp[2][d], hw); DOT2(p3, wp[3][d], hw);
        DOTBLK(0,  hu0.x) DOTBLK(1,  hu0.y) DOTBLK(2,  hu0.z) DOTBLK(3,  hu0.w)
        DOTBLK(4,  hu1.x) DOTBLK(5,  hu1.y) DOTBLK(6,  hu1.z) DOTBLK(7,  hu1.w)
        DOTBLK(8,  hu2.x) DOTBLK(9,  hu2.y) DOTBLK(10, hu2.z) DOTBLK(11, hu2.w)
        DOTBLK(12, hu3.x) DOTBLK(13, hu3.y) DOTBLK(14, hu3.z) DOTBLK(15, hu3.w)
#undef DOTBLK

        // allreduce partial dots over the 4 kc lanes (j bits 0-1)
        p0 += __shfl_xor(p0, 1); p0 += __shfl_xor(p0, 2);
        p1 += __shfl_xor(p1, 1); p1 += __shfl_xor(p1, 2);
        p2 += __shfl_xor(p2, 1); p2 += __shfl_xor(p2, 2);
        p3 += __shfl_xor(p3, 1); p3 += __shfl_xor(p3, 2);

        float si = g0 + p0;   // input gate (pre-activation)
        float sf = g1 + p1;   // forget
        float sg = g2 + p2;   // cell
        float so = g3 + p3;   // output
        float ia = 1.f / (1.f + __expf(-si));
        float fa = 1.f / (1.f + __expf(-sf));
        float ga = 1.f - 2.f / (1.f + __expf(2.f * sg));   // tanh
        float oa = 1.f / (1.f + __expf(-so));
        c = fa * c + ia * ga;
        float th = 1.f - 2.f / (1.f + __expf(2.f * c));
        float h = oa * th;
        if (kc == 0) {
            int tt = dir ? (511 - s) : s;
            out[((size_t)b * NL + tt) * 256 + dir * 128 + hh] = h;
            sm.hbuf[1 - rb][hh] = f2bf(h);
        }
        __syncthreads();
    }
}

// ---------------------------------------------------------------------------
// 5) LayerNorm in-place over last dim (256); one wave per row
// ---------------------------------------------------------------------------
__global__ __launch_bounds__(256) void ln_kernel(float* __restrict__ out,
                                                 const float* __restrict__ gamma,
                                                 const float* __restrict__ beta) {
    int row = blockIdx.x * 4 + (threadIdx.x >> 6);
    int lane = threadIdx.x & 63;
    float* p = out + (size_t)row * 256;
    float4 v = ((const float4*)p)[lane];
    float s = (v.x + v.y) + (v.z + v.w);
    float s2 = (v.x * v.x + v.y * v.y) + (v.z * v.z + v.w * v.w);
    #pragma unroll
    for (int o = 32; o > 0; o >>= 1) {
        s += __shfl_xor(s, o);
        s2 += __shfl_xor(s2, o);
    }
    float mu = s * (1.f / 256.f);
    float var = s2 * (1.f / 256.f) - mu * mu;
    float rs = rsqrtf(var + 1e-5f);
    float4 gv = ((const float4*)gamma)[lane];
    float4 bv = ((const float4*)beta)[lane];
    float4 r;
    r.x = (v.x - mu) * rs * gv.x + bv.x;
    r.y = (v.y - mu) * rs * gv.y + bv.y;
    r.z = (v.z - mu) * rs * gv.z + bv.z;
    r.w = (v.w - mu) * rs * gv.w + bv.w;
    ((float4*)p)[lane] = r;
}

// ---------------------------------------------------------------------------
extern "C" void kernel_launch(void* const* d_in, const int* in_sizes, int n_in,
                              void* d_out, int out_size, void* d_ws, size_t ws_size,
                              hipStream_t stream) {
    (void)in_sizes; (void)n_in; (void)out_size; (void)ws_size;
    const float* x     = (const float*)d_in[0];
    const float* Wproj = (const float*)d_in[1];
    const float* bproj = (const float*)d_in[2];
    const float* Wih_f = (const float*)d_in[3];
    const float* Whh_f = (const float*)d_in[4];
    const float* b_f   = (const float*)d_in[5];
    const float* Wih_b = (const float*)d_in[6];
    const float* Whh_b = (const float*)d_in[7];
    const float* b_b   = (const float*)d_in[8];
    const float* gamma = (const float*)d_in[9];
    const float* beta  = (const float*)d_in[10];
    float* out = (float*)d_out;

    // workspace layout
    char* ws = (char*)d_ws;
    unsigned short* pre  = (unsigned short*)ws;                   // 65536*1024*2 = 134217728
    unsigned short* xbt  = (unsigned short*)(ws + 134217728);     // 65536*256*2  =  33554432
    unsigned short* weff = (unsigned short*)(ws + 167772160);     // 1024*256*2   =    524288
    float*          beff = (float*)(ws + 168296448);              // 1024*4

    convert_kernel<<<16384, 256, 0, stream>>>(x, xbt);
    fold_kernel<<<1024, 256, 0, stream>>>(Wproj, bproj, Wih_f, b_f, Wih_b, b_b, weff, beff);
    gemm_pre<<<dim3(8, 512), 256, 0, stream>>>(xbt, weff, beff, pre);
    scan_kernel<<<dim3(128, 2), 512, 0, stream>>>(pre, Whh_f, Whh_b, out);
    ln_kernel<<<16384, 256, 0, stream>>>(out, gamma, beta);
}

// Round 8
// 572.214 us; speedup vs baseline: 1.0308x; 1.0181x over previous
//
#include <hip/hip_runtime.h>

// Problem constants: B=128, L=512, D=256, H=128, 4H=512, both dirs fused NG=1024
#define NB 128
#define NL 512
#define ND 256
#define NG 1024

typedef __attribute__((ext_vector_type(8))) short bfv8;
typedef __attribute__((ext_vector_type(4))) float f32x4;
typedef __attribute__((ext_vector_type(4))) unsigned u32x4;

__device__ __forceinline__ unsigned short f2bf(float f) {
    unsigned u = __float_as_uint(f);
    u += 0x7fffu + ((u >> 16) & 1u);   // round-to-nearest-even
    return (unsigned short)(u >> 16);
}
__device__ __forceinline__ float bf2f(unsigned short u) {
    return __uint_as_float(((unsigned)u) << 16);
}

// ---------------------------------------------------------------------------
// 1) convert+transpose: xbt[l*128+b][d] = bf16(x[b][l][d])
// ---------------------------------------------------------------------------
__global__ __launch_bounds__(256) void convert_kernel(const float* __restrict__ x,
                                                      unsigned short* __restrict__ xbt) {
    size_t t = (size_t)blockIdx.x * 256 + threadIdx.x;
    size_t e = t * 4;                       // flat idx into x, 4 floats per thread
    int d = (int)(e & 255u);
    int l = (int)((e >> 8) & 511u);
    int b = (int)(e >> 17);
    float4 v = *(const float4*)(x + e);
    ushort4 o;
    o.x = f2bf(v.x); o.y = f2bf(v.y); o.z = f2bf(v.z); o.w = f2bf(v.w);
    *(ushort4*)(xbt + ((size_t)(l * NB + b)) * ND + d) = o;
}

// ---------------------------------------------------------------------------
// 2) fold: Weff[g][k] = sum_d Wih[g][d] * W_proj[d][k]  (bf16 out)
//    beff[g] = b[g] + sum_d Wih[g][d] * b_proj[d]
// ---------------------------------------------------------------------------
__global__ __launch_bounds__(256) void fold_kernel(const float* __restrict__ Wproj,
                                                   const float* __restrict__ bproj,
                                                   const float* __restrict__ Wih_f,
                                                   const float* __restrict__ b_f,
                                                   const float* __restrict__ Wih_b,
                                                   const float* __restrict__ b_b,
                                                   unsigned short* __restrict__ weff,
                                                   float* __restrict__ beff) {
    int g = blockIdx.x;            // 0..1023
    int k = threadIdx.x;           // 0..255
    const float* Wih = (g < 512) ? (Wih_f + (size_t)g * ND) : (Wih_b + (size_t)(g - 512) * ND);
    float acc = 0.f;
    for (int d = 0; d < ND; ++d)
        acc += Wih[d] * Wproj[(size_t)d * ND + k];
    weff[(size_t)g * ND + k] = f2bf(acc);
    if (k == 0) {
        float ab = (g < 512) ? b_f[g] : b_b[g - 512];
        for (int d = 0; d < ND; ++d) ab += Wih[d] * bproj[d];
        beff[g] = ab;
    }
}

// ---------------------------------------------------------------------------
// 3) pre-GEMM: C[r][g] = bf16( A[r][:] . Bw[g][:] + bias[g] )
//    128x128 tile, BK=32, 4 waves (2x2), 16x16x32 bf16 MFMA, XOR-swizzled LDS
// ---------------------------------------------------------------------------
__global__ __launch_bounds__(256, 2) void gemm_pre(const unsigned short* __restrict__ A,
                                                   const unsigned short* __restrict__ Bw,
                                                   const float* __restrict__ bias,
                                                   unsigned short* __restrict__ C) {
    __shared__ unsigned short As[128 * 32];
    __shared__ unsigned short Bs[128 * 32];
    const int tid = threadIdx.x;
    const int lane = tid & 63;
    const int wid = tid >> 6;
    const int m0 = blockIdx.y * 128;
    const int n0 = blockIdx.x * 128;
    const int wm = (wid >> 1) * 64;
    const int wn = (wid & 1) * 64;

    f32x4 acc[4][4] = {};

    const int row0 = tid >> 2;               // 0..63
    const int row1 = row0 + 64;
    const int co = (tid & 3) * 8;            // element col offset (8 bf16 = 16B)
    const int sw = (((tid & 3) << 4) ^ ((row0 & 3) << 4)) >> 1;

    bfv8 ra0 = *(const bfv8*)(A + (size_t)(m0 + row0) * ND + co);
    bfv8 ra1 = *(const bfv8*)(A + (size_t)(m0 + row1) * ND + co);
    bfv8 rb0 = *(const bfv8*)(Bw + (size_t)(n0 + row0) * ND + co);
    bfv8 rb1 = *(const bfv8*)(Bw + (size_t)(n0 + row1) * ND + co);

    for (int it = 0; it < 8; ++it) {
        __syncthreads();
        *(bfv8*)(As + row0 * 32 + sw) = ra0;
        *(bfv8*)(As + row1 * 32 + sw) = ra1;
        *(bfv8*)(Bs + row0 * 32 + sw) = rb0;
        *(bfv8*)(Bs + row1 * 32 + sw) = rb1;
        const int k1 = ((it + 1) & 7) * 32;
        ra0 = *(const bfv8*)(A + (size_t)(m0 + row0) * ND + k1 + co);
        ra1 = *(const bfv8*)(A + (size_t)(m0 + row1) * ND + k1 + co);
        rb0 = *(const bfv8*)(Bw + (size_t)(n0 + row0) * ND + k1 + co);
        rb1 = *(const bfv8*)(Bw + (size_t)(n0 + row1) * ND + k1 + co);
        __syncthreads();

        const int r = lane & 15;
        const int kq = lane >> 4;
        bfv8 af[4], bfr[4];
        #pragma unroll
        for (int m = 0; m < 4; ++m) {
            int rw = wm + m * 16 + r;
            af[m] = *(const bfv8*)(As + rw * 32 + (((kq << 4) ^ ((rw & 3) << 4)) >> 1));
        }
        #pragma unroll
        for (int n = 0; n < 4; ++n) {
            int rw = wn + n * 16 + r;
            bfr[n] = *(const bfv8*)(Bs + rw * 32 + (((kq << 4) ^ ((rw & 3) << 4)) >> 1));
        }
        #pragma unroll
        for (int m = 0; m < 4; ++m)
            #pragma unroll
            for (int n = 0; n < 4; ++n)
                acc[m][n] = __builtin_amdgcn_mfma_f32_16x16x32_bf16(af[m], bfr[n], acc[m][n], 0, 0, 0);
    }

    const int r = lane & 15;
    const int rq = lane >> 4;
    #pragma unroll
    for (int n = 0; n < 4; ++n) {
        int col = n0 + wn + n * 16 + r;
        float bv = bias[col];
        #pragma unroll
        for (int m = 0; m < 4; ++m) {
            #pragma unroll
            for (int v = 0; v < 4; ++v) {
                int rowg = m0 + wm + m * 16 + rq * 4 + v;
                C[(size_t)rowg * NG + col] = f2bf(acc[m][n][v] + bv);
            }
        }
    }
}

// ---------------------------------------------------------------------------
// 4) LSTM scan. Diagnosis after r1-r7: step cost was a CONSTANT ~2350cy across
//    every structure (f32 broadcast / bf16 dot2 K-split / resident weights) ->
//    not throughput-bound. Cause: a global load (pre) + store (out) issued in
//    EVERY step, and the compiler's mandatory `s_waitcnt vmcnt(0)` before each
//    s_barrier drains them -> every step pays full HBM latency (~900cy) +
//    LDS/shfl/exp chain, no cross-wave hiding (all waves same step).
//    FIX: batch pre-loads 8 steps ahead (double-buffered in constant-indexed
//    registers) and batch out-stores (8-step register FIFO). VMEM is issued
//    once per 8 steps -> only the first of 8 barriers drains a latency.
//    Keeps r6/r7 K-split compute: thread j: hh=j>>2 owns 4 gate rows, kc=j&3
//    owns a 32-elem h chunk; 16 v_dot2_f32_bf16/row; shfl_xor allreduce.
//    LDS occupancy pin (>80KiB) kept: 1 block/CU -> 256-VGPR budget (r7
//    verified weights stay resident under it).
// ---------------------------------------------------------------------------
#define DOT2(p, w, h) asm("v_dot2_f32_bf16 %0, %1, %2, %0" : "+v"(p) : "v"(w), "v"(h))

struct ScanSM {
    unsigned short hbuf[2][128];   // bf16 h, double buffered
    char occupancy_pin[82176];     // push block LDS > 81920 B -> 1 block/CU
};

__device__ __forceinline__ void load8(float (&P)[8][4], int sbase, int dir, int b,
                                      size_t pbase, const unsigned short* __restrict__ pre) {
    #pragma unroll
    for (int k = 0; k < 8; ++k) {
        int ss = sbase + k; ss = ss < 511 ? ss : 511;
        int tt = dir ? (511 - ss) : ss;
        const unsigned short* q = pre + (size_t)(tt * NB + b) * NG + pbase;
        P[k][0] = bf2f(q[0]);  P[k][1] = bf2f(q[128]);
        P[k][2] = bf2f(q[256]); P[k][3] = bf2f(q[384]);
    }
}

__device__ __forceinline__ void step8(const float (&P)[8][4], int sbase, int dir, int b,
                                      int kc, int hh, const unsigned (&wp)[4][16],
                                      ScanSM& sm, float& c, float* __restrict__ out) {
    float hsave[8];
    #pragma unroll
    for (int k = 0; k < 8; ++k) {
        const int s = sbase + k;
        const int rb = s & 1;
        const bfv8* hv8 = (const bfv8*)&sm.hbuf[rb][kc * 32];
        u32x4 hu0 = __builtin_bit_cast(u32x4, hv8[0]);
        u32x4 hu1 = __builtin_bit_cast(u32x4, hv8[1]);
        u32x4 hu2 = __builtin_bit_cast(u32x4, hv8[2]);
        u32x4 hu3 = __builtin_bit_cast(u32x4, hv8[3]);

        float p0 = 0.f, p1 = 0.f, p2 = 0.f, p3 = 0.f;
#define DOTBLK(d, hw) \
        DOT2(p0, wp[0][d], hw); DOT2(p1, wp[1][d], hw); \
        DOT2(p2, wp[2][d], hw); DOT2(p3, wp[3][d], hw);
        DOTBLK(0,  hu0.x) DOTBLK(1,  hu0.y) DOTBLK(2,  hu0.z) DOTBLK(3,  hu0.w)
        DOTBLK(4,  hu1.x) DOTBLK(5,  hu1.y) DOTBLK(6,  hu1.z) DOTBLK(7,  hu1.w)
        DOTBLK(8,  hu2.x) DOTBLK(9,  hu2.y) DOTBLK(10, hu2.z) DOTBLK(11, hu2.w)
        DOTBLK(12, hu3.x) DOTBLK(13, hu3.y) DOTBLK(14, hu3.z) DOTBLK(15, hu3.w)
#undef DOTBLK

        // allreduce partial dots over the 4 kc lanes (j bits 0-1)
        p0 += __shfl_xor(p0, 1); p0 += __shfl_xor(p0, 2);
        p1 += __shfl_xor(p1, 1); p1 += __shfl_xor(p1, 2);
        p2 += __shfl_xor(p2, 1); p2 += __shfl_xor(p2, 2);
        p3 += __shfl_xor(p3, 1); p3 += __shfl_xor(p3, 2);

        float si = P[k][0] + p0;
        float sf = P[k][1] + p1;
        float sg = P[k][2] + p2;
        float so = P[k][3] + p3;
        float ia = 1.f / (1.f + __expf(-si));
        float fa = 1.f / (1.f + __expf(-sf));
        float ga = 1.f - 2.f / (1.f + __expf(2.f * sg));   // tanh
        float oa = 1.f / (1.f + __expf(-so));
        c = fa * c + ia * ga;
        float th = 1.f - 2.f / (1.f + __expf(2.f * c));
        float h = oa * th;
        if (kc == 0) {
            hsave[k] = h;
            sm.hbuf[1 - rb][hh] = f2bf(h);
        }
        __syncthreads();
    }
    // batched out-stores: issued once per 8 steps, drained at next group's
    // first barrier together with the next batch's loads
    if (kc == 0) {
        #pragma unroll
        for (int k = 0; k < 8; ++k) {
            int tt = dir ? (511 - (sbase + k)) : (sbase + k);
            out[((size_t)b * NL + tt) * 256 + dir * 128 + hh] = hsave[k];
        }
    }
}

__global__ void __launch_bounds__(512, 2)
scan_kernel(const unsigned short* __restrict__ pre,
            const float* __restrict__ Whh_f,
            const float* __restrict__ Whh_b,
            float* __restrict__ out) {
    const int b = blockIdx.x;
    const int dir = blockIdx.y;
    const int j = threadIdx.x;
    const int kc = j & 3;            // K-chunk: h[32*kc .. 32*kc+32)
    const int hh = j >> 2;           // hidden unit

    const float* __restrict__ Wd = dir ? Whh_b : Whh_f;

    __shared__ ScanSM sm;

    // pack weights bf16: wp[t][d] = (w[2d+1]<<16)|w[2d], rows t*128+hh, cols kc*32..
    unsigned wp[4][16];
    #pragma unroll
    for (int t = 0; t < 4; ++t) {
        const float4* wr = (const float4*)(Wd + (size_t)(t * 128 + hh) * 128 + kc * 32);
        #pragma unroll
        for (int q = 0; q < 8; ++q) {
            float4 v = wr[q];
            wp[t][2 * q]     = (unsigned)f2bf(v.x) | ((unsigned)f2bf(v.y) << 16);
            wp[t][2 * q + 1] = (unsigned)f2bf(v.z) | ((unsigned)f2bf(v.w) << 16);
        }
    }

    if (j < 128) { sm.hbuf[0][j] = 0; sm.hbuf[1][j] = 0; }
    float c = 0.f;
    const size_t pbase = (size_t)dir * 512 + hh;

    float pA[8][4], pB[8][4];
    load8(pA, 0, dir, b, pbase, pre);
    __syncthreads();

    for (int s16 = 0; s16 < 512; s16 += 16) {
        load8(pB, s16 + 8, dir, b, pbase, pre);
        step8(pA, s16, dir, b, kc, hh, wp, sm, c, out);
        load8(pA, s16 + 16, dir, b, pbase, pre);   // final iter: clamped (unused)
        step8(pB, s16 + 8, dir, b, kc, hh, wp, sm, c, out);
    }
}

// ---------------------------------------------------------------------------
// 5) LayerNorm in-place over last dim (256); one wave per row
// ---------------------------------------------------------------------------
__global__ __launch_bounds__(256) void ln_kernel(float* __restrict__ out,
                                                 const float* __restrict__ gamma,
                                                 const float* __restrict__ beta) {
    int row = blockIdx.x * 4 + (threadIdx.x >> 6);
    int lane = threadIdx.x & 63;
    float* p = out + (size_t)row * 256;
    float4 v = ((const float4*)p)[lane];
    float s = (v.x + v.y) + (v.z + v.w);
    float s2 = (v.x * v.x + v.y * v.y) + (v.z * v.z + v.w * v.w);
    #pragma unroll
    for (int o = 32; o > 0; o >>= 1) {
        s += __shfl_xor(s, o);
        s2 += __shfl_xor(s2, o);
    }
    float mu = s * (1.f / 256.f);
    float var = s2 * (1.f / 256.f) - mu * mu;
    float rs = rsqrtf(var + 1e-5f);
    float4 gv = ((const float4*)gamma)[lane];
    float4 bv = ((const float4*)beta)[lane];
    float4 r;
    r.x = (v.x - mu) * rs * gv.x + bv.x;
    r.y = (v.y - mu) * rs * gv.y + bv.y;
    r.z = (v.z - mu) * rs * gv.z + bv.z;
    r.w = (v.w - mu) * rs * gv.w + bv.w;
    ((float4*)p)[lane] = r;
}

// ---------------------------------------------------------------------------
extern "C" void kernel_launch(void* const* d_in, const int* in_sizes, int n_in,
                              void* d_out, int out_size, void* d_ws, size_t ws_size,
                              hipStream_t stream) {
    (void)in_sizes; (void)n_in; (void)out_size; (void)ws_size;
    const float* x     = (const float*)d_in[0];
    const float* Wproj = (const float*)d_in[1];
    const float* bproj = (const float*)d_in[2];
    const float* Wih_f = (const float*)d_in[3];
    const float* Whh_f = (const float*)d_in[4];
    const float* b_f   = (const float*)d_in[5];
    const float* Wih_b = (const float*)d_in[6];
    const float* Whh_b = (const float*)d_in[7];
    const float* b_b   = (const float*)d_in[8];
    const float* gamma = (const float*)d_in[9];
    const float* beta  = (const float*)d_in[10];
    float* out = (float*)d_out;

    // workspace layout
    char* ws = (char*)d_ws;
    unsigned short* pre  = (unsigned short*)ws;                   // 65536*1024*2 = 134217728
    unsigned short* xbt  = (unsigned short*)(ws + 134217728);     // 65536*256*2  =  33554432
    unsigned short* weff = (unsigned short*)(ws + 167772160);     // 1024*256*2   =    524288
    float*          beff = (float*)(ws + 168296448);              // 1024*4

    convert_kernel<<<16384, 256, 0, stream>>>(x, xbt);
    fold_kernel<<<1024, 256, 0, stream>>>(Wproj, bproj, Wih_f, b_f, Wih_b, b_b, weff, beff);
    gemm_pre<<<dim3(8, 512), 256, 0, stream>>>(xbt, weff, beff, pre);
    scan_kernel<<<dim3(128, 2), 512, 0, stream>>>(pre, Whh_f, Whh_b, out);
    ln_kernel<<<16384, 256, 0, stream>>>(out, gamma, beta);
}